// Round 2
// baseline (5057.659 us; speedup 1.0000x reference)
//
#include <hip/hip_runtime.h>
#include <stdint.h>

typedef unsigned short ushort_t;
typedef unsigned int u32;
typedef unsigned long long u64;

#define NC_ 16384
#define NS_ 16384
#define DIM 2688
#define D4 (DIM / 4)       // 672 float4 per row
#define KSTEPS (DIM / 32)  // 84

typedef __attribute__((ext_vector_type(8))) short short8;
typedef __attribute__((ext_vector_type(16))) float f32x16;

// ---------- helpers ----------

__device__ inline ushort_t f2bf(float x) {
  u32 u = __float_as_uint(x);
  u32 r = u + 0x7FFFu + ((u >> 16) & 1u);  // RNE
  return (ushort_t)(r >> 16);
}
__device__ inline float bf2f(ushort_t b) { return __uint_as_float(((u32)b) << 16); }

// monotone float -> uint mapping (finite inputs)
__device__ inline u32 fkey(float f) {
  u32 u = __float_as_uint(f);
  return (u & 0x80000000u) ? ~u : (u | 0x80000000u);
}

__device__ inline void async16(const void* g, void* l) {
  __builtin_amdgcn_global_load_lds(
      (const __attribute__((address_space(1))) u32*)g,
      (__attribute__((address_space(3))) u32*)l, 16, 0, 0);
}

// Swizzled ushort offset of (row r, 16B-chunk q) within a [rows][32-ushort] tile.
// Rows paired into 128B lines of 8 chunks; chunk index XOR'd with row-pair index
// so every 16-lane read group covers all 8 bank slots exactly twice (2-way=free).
__device__ inline int swz(int r, int q) {
  return ((r >> 1) << 6) + (((((r & 1) << 2) | q) ^ ((r >> 1) & 7)) << 3);
}

// ---------- kernel 1: split content fp32 -> bf16 hi/lo ----------

__global__ __launch_bounds__(256) void content_split_kernel(
    const float* __restrict__ fc, ushort_t* __restrict__ c_hi, ushort_t* __restrict__ c_lo) {
  size_t i = (size_t)blockIdx.x * 256 + threadIdx.x;
  if (i >= (size_t)NC_ * DIM / 4) return;
  float4 v = ((const float4*)fc)[i];
  ushort4 h, l;
  h.x = f2bf(v.x); l.x = f2bf(v.x - bf2f(h.x));
  h.y = f2bf(v.y); l.y = f2bf(v.y - bf2f(h.y));
  h.z = f2bf(v.z); l.z = f2bf(v.z - bf2f(h.z));
  h.w = f2bf(v.w); l.w = f2bf(v.w - bf2f(h.w));
  ((ushort4*)c_hi)[i] = h;
  ((ushort4*)c_lo)[i] = l;
}

// ---------- kernel 2: style row-normalize + split ----------

__global__ __launch_bounds__(256) void style_split_kernel(
    const float* __restrict__ fs, ushort_t* __restrict__ s_hi, ushort_t* __restrict__ s_lo) {
  const int s = blockIdx.x, t = threadIdx.x;
  const float4* row = (const float4*)(fs + (size_t)s * DIM);
  float ss = 0.f;
  for (int i = t; i < D4; i += 256) {
    float4 v = row[i];
    ss += v.x * v.x + v.y * v.y + v.z * v.z + v.w * v.w;
  }
#pragma unroll
  for (int off = 32; off >= 1; off >>= 1) ss += __shfl_xor(ss, off, 64);
  __shared__ float wsum[4];
  if ((t & 63) == 0) wsum[t >> 6] = ss;
  __syncthreads();
  float scale = rsqrtf(wsum[0] + wsum[1] + wsum[2] + wsum[3] + 1e-8f);
  ushort4* h4 = (ushort4*)(s_hi + (size_t)s * DIM);
  ushort4* l4 = (ushort4*)(s_lo + (size_t)s * DIM);
  for (int i = t; i < D4; i += 256) {
    float4 v = row[i];
    float x = v.x * scale, y = v.y * scale, z = v.z * scale, w = v.w * scale;
    ushort4 h, l;
    h.x = f2bf(x); l.x = f2bf(x - bf2f(h.x));
    h.y = f2bf(y); l.y = f2bf(y - bf2f(h.y));
    h.z = f2bf(z); l.z = f2bf(z - bf2f(h.z));
    h.w = f2bf(w); l.w = f2bf(w - bf2f(h.w));
    h4[i] = h;
    l4[i] = l;
  }
}

// ---------- kernel 3: 128x256-tile sim GEMM (bf16x3, 32x32x16 MFMA) + row argmax ----------
// Block tile 128(M) x 256(N), 4 waves in 2x2 grid, 64x128 per wave.
// LDS tiles chunk-swizzled (swz) for conflict-free ds_read_b128; global_load_lds
// destination stays linear, so the SOURCE address is pre-swizzled (same involution).
// Total LDS exactly 48 KiB (red[] aliased into the tile area, used only after the
// K-loop) -> 3 blocks/CU resident.
// partial[m * 64 + sb] = packed (fkey(max sim) << 32) | (0xFFFFFFFF - argmax_col)

__global__ __launch_bounds__(256, 3) void sim_argmax_kernel(
    const ushort_t* __restrict__ c_hi, const ushort_t* __restrict__ c_lo,
    const ushort_t* __restrict__ s_hi, const ushort_t* __restrict__ s_lo,
    u64* __restrict__ partial) {
  __shared__ __align__(16) ushort_t lds[24576];  // 48 KiB total

  ushort_t* la_hi = lds;           // 128 rows * 32
  ushort_t* la_lo = lds + 4096;
  ushort_t* lb_hi = lds + 8192;    // 256 rows * 32
  ushort_t* lb_lo = lds + 16384;
  u64 (*red)[2] = (u64(*)[2])lds;  // 128x2 u64 = 2 KiB, aliases la_hi (dead post-loop)

  const int t = threadIdx.x;
  const int bid = blockIdx.x;  // 8192 blocks: 128 cb x 64 sb
  // 16x16 block supertiles for LLC/L2 locality
  const int grp = bid >> 8;    // 0..31
  const int wi = bid & 255;
  const int cb = (grp & 7) * 16 + (wi & 15);   // 0..127
  const int sb = (grp >> 3) * 16 + (wi >> 4);  // 0..63

  const ushort_t* gah = c_hi + (size_t)cb * 128 * DIM;
  const ushort_t* gal = c_lo + (size_t)cb * 128 * DIM;
  const ushort_t* gbh = s_hi + (size_t)sb * 256 * DIM;
  const ushort_t* gbl = s_lo + (size_t)sb * 256 * DIM;

  const int lane = t & 63;
  const int wave = t >> 6;
  const int wy = wave >> 1, wx = wave & 1;  // 2x2 wave grid; wave tile 64(M) x 128(N)
  const int lr = lane & 31;                 // row within a 32-row MFMA block
  const int kq = lane >> 5;                 // K-offset group: k = kq*8 + j

  f32x16 acc[2][4];
#pragma unroll
  for (int i = 0; i < 2; i++)
#pragma unroll
    for (int j = 0; j < 4; j++)
#pragma unroll
      for (int r = 0; r < 16; r++) acc[i][j][r] = 0.f;

  const int tw = t & 192;  // wave base within 256 threads

  for (int ks = 0; ks < KSTEPS; ++ks) {
    const int kel = ks * 32;
    // A tiles: 512 chunks each (128 rows x 4 chunks)
#pragma unroll
    for (int j = 0; j < 2; ++j) {
      int e = j * 256 + t;  // linear LDS 16B-chunk index
      int rp = e >> 3;
      int cc = (e & 7) ^ (rp & 7);          // pre-swizzled source chunk
      int row = (rp << 1) | (cc >> 2);
      size_t goff = (size_t)row * DIM + kel + (cc & 3) * 8;  // ushort units
      int loff = (j * 256 + tw) * 8;                         // wave-uniform LDS base
      async16(gah + goff, la_hi + loff);
      async16(gal + goff, la_lo + loff);
    }
    // B tiles: 1024 chunks each (256 rows x 4 chunks)
#pragma unroll
    for (int j = 0; j < 4; ++j) {
      int e = j * 256 + t;
      int rp = e >> 3;
      int cc = (e & 7) ^ (rp & 7);
      int row = (rp << 1) | (cc >> 2);
      size_t goff = (size_t)row * DIM + kel + (cc & 3) * 8;
      int loff = (j * 256 + tw) * 8;
      async16(gbh + goff, lb_hi + loff);
      async16(gbl + goff, lb_lo + loff);
    }
    __syncthreads();

    // A fragments: [mi][ksub], row = wy*64 + mi*32 + lr, k-chunk = ksub*2 + kq
    short8 ah[2][2], al[2][2];
#pragma unroll
    for (int mi = 0; mi < 2; ++mi)
#pragma unroll
      for (int ku = 0; ku < 2; ++ku) {
        int r = swz(wy * 64 + mi * 32 + lr, ku * 2 + kq);
        ah[mi][ku] = *(const short8*)(la_hi + r);
        al[mi][ku] = *(const short8*)(la_lo + r);
      }
#pragma unroll
    for (int h = 0; h < 2; ++h) {
      short8 bh[2][2], bl[2][2];
#pragma unroll
      for (int nj = 0; nj < 2; ++nj)
#pragma unroll
        for (int ku = 0; ku < 2; ++ku) {
          int r = swz(wx * 128 + (h * 2 + nj) * 32 + lr, ku * 2 + kq);
          bh[nj][ku] = *(const short8*)(lb_hi + r);
          bl[nj][ku] = *(const short8*)(lb_lo + r);
        }
#pragma unroll
      for (int mi = 0; mi < 2; ++mi)
#pragma unroll
        for (int nj = 0; nj < 2; ++nj) {
          int ni = h * 2 + nj;
#pragma unroll
          for (int ku = 0; ku < 2; ++ku) {
            acc[mi][ni] = __builtin_amdgcn_mfma_f32_32x32x16_bf16(ah[mi][ku], bh[nj][ku], acc[mi][ni], 0, 0, 0);
            acc[mi][ni] = __builtin_amdgcn_mfma_f32_32x32x16_bf16(ah[mi][ku], bl[nj][ku], acc[mi][ni], 0, 0, 0);
            acc[mi][ni] = __builtin_amdgcn_mfma_f32_32x32x16_bf16(al[mi][ku], bh[nj][ku], acc[mi][ni], 0, 0, 0);
          }
        }
    }
    __syncthreads();
  }

  // per-row argmax over this block's 256 style columns
  // C layout (32x32x16): col = lane&31, row = (reg&3) + 8*(reg>>2) + 4*(lane>>5)
#pragma unroll
  for (int mi = 0; mi < 2; ++mi) {
#pragma unroll
    for (int r = 0; r < 16; ++r) {
      float bv = acc[mi][0][r];
      int bn = 0;
#pragma unroll
      for (int ni = 1; ni < 4; ++ni) {
        float v = acc[mi][ni][r];
        if (v > bv) { bv = v; bn = ni; }
      }
      u32 colg = (u32)(sb * 256 + wx * 128 + bn * 32 + lr);
      u64 key = ((u64)fkey(bv) << 32) | (u64)(0xFFFFFFFFu - colg);
      // reduce over the 32 lanes holding this row (offsets <32 stay in-half)
#pragma unroll
      for (int off = 16; off >= 1; off >>= 1) {
        u64 o = __shfl_xor((unsigned long long)key, off, 64);
        if (o > key) key = o;
      }
      int row_local = wy * 64 + mi * 32 + (r & 3) + 8 * (r >> 2) + 4 * kq;
      if (lr == 0) red[row_local][wx] = key;
    }
  }
  __syncthreads();
  if (t < 128) {
    u64 k0 = red[t][0], k1 = red[t][1];
    u64 b = k0 > k1 ? k0 : k1;
    partial[((size_t)(cb * 128 + t)) * 64 + sb] = b;
  }
}

// ---------- kernel 4: final 64-way reduce + gather ----------

__global__ __launch_bounds__(256) void argmax_gather_kernel(
    const u64* __restrict__ partial, const float* __restrict__ fs, float* __restrict__ out) {
  const int m = blockIdx.x, t = threadIdx.x;
  __shared__ u64 sbest;
  if (t < 64) {
    u64 key = partial[(size_t)m * 64 + t];
#pragma unroll
    for (int off = 32; off >= 1; off >>= 1) {
      u64 o = __shfl_xor((unsigned long long)key, off, 64);
      if (o > key) key = o;
    }
    if (t == 0) sbest = key;
  }
  __syncthreads();
  u64 best = sbest;
  u32 col = 0xFFFFFFFFu - (u32)best;
  const float4* src = (const float4*)(fs + (size_t)col * DIM);
  float4* dst = (float4*)(out + (size_t)m * DIM);
  for (int i = t; i < D4; i += 256) dst[i] = src[i];
}

// ---------- launch ----------

extern "C" void kernel_launch(void* const* d_in, const int* in_sizes, int n_in,
                              void* d_out, int out_size, void* d_ws, size_t ws_size,
                              hipStream_t stream) {
  const float* fc = (const float*)d_in[0];
  const float* fs = (const float*)d_in[1];
  float* out = (float*)d_out;

  ushort_t* c_hi = (ushort_t*)d_ws;
  ushort_t* c_lo = c_hi + (size_t)NC_ * DIM;
  ushort_t* s_hi = c_lo + (size_t)NC_ * DIM;
  ushort_t* s_lo = s_hi + (size_t)NS_ * DIM;
  u64* partial = (u64*)(s_lo + (size_t)NS_ * DIM);  // 16384 * 64 u64

  content_split_kernel<<<(NC_ * DIM / 4 + 255) / 256, 256, 0, stream>>>(fc, c_hi, c_lo);
  style_split_kernel<<<NS_, 256, 0, stream>>>(fs, s_hi, s_lo);
  sim_argmax_kernel<<<8192, 256, 0, stream>>>(c_hi, c_lo, s_hi, s_lo, partial);
  argmax_gather_kernel<<<NC_, 256, 0, stream>>>(partial, fs, out);
}

// Round 3
// 3799.121 us; speedup vs baseline: 1.3313x; 1.3313x over previous
//
#include <hip/hip_runtime.h>
#include <stdint.h>

typedef unsigned short ushort_t;
typedef unsigned int u32;
typedef unsigned long long u64;

#define NC_ 16384
#define NS_ 16384
#define DIM 2688
#define D4 (DIM / 4)       // 672 float4 per row
#define KSTEPS (DIM / 32)  // 84

typedef __attribute__((ext_vector_type(8))) short short8;
typedef __attribute__((ext_vector_type(4))) float f32x4;

// ---------- helpers ----------

__device__ inline ushort_t f2bf(float x) {
  u32 u = __float_as_uint(x);
  u32 r = u + 0x7FFFu + ((u >> 16) & 1u);  // RNE
  return (ushort_t)(r >> 16);
}
__device__ inline float bf2f(ushort_t b) { return __uint_as_float(((u32)b) << 16); }

// monotone float -> uint mapping (finite inputs)
__device__ inline u32 fkey(float f) {
  u32 u = __float_as_uint(f);
  return (u & 0x80000000u) ? ~u : (u | 0x80000000u);
}

__device__ inline void async16(const void* g, void* l) {
  __builtin_amdgcn_global_load_lds(
      (const __attribute__((address_space(1))) u32*)g,
      (__attribute__((address_space(3))) u32*)l, 16, 0, 0);
}

// Swizzled ushort offset of (row r, 16B-chunk q) within a [rows][32-ushort] tile.
// Rows paired into 128B lines of 8 chunks; chunk index XOR'd with row-pair index
// so each 16-lane quarter-wave read covers all 8 bank slots exactly twice
// (2-way = free). Verified 0 SQ_LDS_BANK_CONFLICT with the 16x16x32 read pattern.
__device__ inline int swz(int r, int q) {
  return ((r >> 1) << 6) + (((((r & 1) << 2) | q) ^ ((r >> 1) & 7)) << 3);
}

// ---------- kernel 1: split content fp32 -> bf16 hi/lo ----------

__global__ __launch_bounds__(256) void content_split_kernel(
    const float* __restrict__ fc, ushort_t* __restrict__ c_hi, ushort_t* __restrict__ c_lo) {
  size_t i = (size_t)blockIdx.x * 256 + threadIdx.x;
  if (i >= (size_t)NC_ * DIM / 4) return;
  float4 v = ((const float4*)fc)[i];
  ushort4 h, l;
  h.x = f2bf(v.x); l.x = f2bf(v.x - bf2f(h.x));
  h.y = f2bf(v.y); l.y = f2bf(v.y - bf2f(h.y));
  h.z = f2bf(v.z); l.z = f2bf(v.z - bf2f(h.z));
  h.w = f2bf(v.w); l.w = f2bf(v.w - bf2f(h.w));
  ((ushort4*)c_hi)[i] = h;
  ((ushort4*)c_lo)[i] = l;
}

// ---------- kernel 2: style row-normalize + split ----------

__global__ __launch_bounds__(256) void style_split_kernel(
    const float* __restrict__ fs, ushort_t* __restrict__ s_hi, ushort_t* __restrict__ s_lo) {
  const int s = blockIdx.x, t = threadIdx.x;
  const float4* row = (const float4*)(fs + (size_t)s * DIM);
  float ss = 0.f;
  for (int i = t; i < D4; i += 256) {
    float4 v = row[i];
    ss += v.x * v.x + v.y * v.y + v.z * v.z + v.w * v.w;
  }
#pragma unroll
  for (int off = 32; off >= 1; off >>= 1) ss += __shfl_xor(ss, off, 64);
  __shared__ float wsum[4];
  if ((t & 63) == 0) wsum[t >> 6] = ss;
  __syncthreads();
  float scale = rsqrtf(wsum[0] + wsum[1] + wsum[2] + wsum[3] + 1e-8f);
  ushort4* h4 = (ushort4*)(s_hi + (size_t)s * DIM);
  ushort4* l4 = (ushort4*)(s_lo + (size_t)s * DIM);
  for (int i = t; i < D4; i += 256) {
    float4 v = row[i];
    float x = v.x * scale, y = v.y * scale, z = v.z * scale, w = v.w * scale;
    ushort4 h, l;
    h.x = f2bf(x); l.x = f2bf(x - bf2f(h.x));
    h.y = f2bf(y); l.y = f2bf(y - bf2f(h.y));
    h.z = f2bf(z); l.z = f2bf(z - bf2f(h.z));
    h.w = f2bf(w); l.w = f2bf(w - bf2f(h.w));
    h4[i] = h;
    l4[i] = l;
  }
}

// ---------- kernel 3: 128x256-tile sim GEMM (bf16x3, 16x16x32 MFMA) + row argmax ----------
// Block tile 128(M) x 256(N), 4 waves in 2x2 grid, 64x128 per wave.
// LDS tiles chunk-swizzled (swz) for conflict-free ds_read_b128; global_load_lds
// destination stays linear, so the SOURCE address is pre-swizzled (same involution).
// Total LDS exactly 48 KiB (red[] aliased into tile area, used only after the
// K-loop) -> 3 blocks/CU resident (verified: 49152 B gives 35% occupancy).
// partial[m * 64 + sb] = packed (fkey(max sim) << 32) | (0xFFFFFFFF - argmax_col)

__global__ __launch_bounds__(256, 2) void sim_argmax_kernel(
    const ushort_t* __restrict__ c_hi, const ushort_t* __restrict__ c_lo,
    const ushort_t* __restrict__ s_hi, const ushort_t* __restrict__ s_lo,
    u64* __restrict__ partial) {
  __shared__ __align__(16) ushort_t lds[24576];  // 48 KiB total

  ushort_t* la_hi = lds;           // 128 rows * 32
  ushort_t* la_lo = lds + 4096;
  ushort_t* lb_hi = lds + 8192;    // 256 rows * 32
  ushort_t* lb_lo = lds + 16384;
  u64 (*red)[2] = (u64(*)[2])lds;  // 128x2 u64 = 2 KiB, aliases la_hi (dead post-loop)

  const int t = threadIdx.x;
  const int bid = blockIdx.x;  // 8192 blocks: 128 cb x 64 sb
  // 16x16 block supertiles for LLC/L2 locality
  const int grp = bid >> 8;    // 0..31
  const int wi = bid & 255;
  const int cb = (grp & 7) * 16 + (wi & 15);   // 0..127
  const int sb = (grp >> 3) * 16 + (wi >> 4);  // 0..63

  const ushort_t* gah = c_hi + (size_t)cb * 128 * DIM;
  const ushort_t* gal = c_lo + (size_t)cb * 128 * DIM;
  const ushort_t* gbh = s_hi + (size_t)sb * 256 * DIM;
  const ushort_t* gbl = s_lo + (size_t)sb * 256 * DIM;

  const int lane = t & 63;
  const int wave = t >> 6;
  const int wy = wave >> 1, wx = wave & 1;  // 2x2 wave grid; wave tile 64(M) x 128(N)
  const int lm = lane & 15, q = lane >> 4;

  f32x4 acc[4][8];
#pragma unroll
  for (int i = 0; i < 4; i++)
#pragma unroll
    for (int j = 0; j < 8; j++) acc[i][j] = (f32x4){0.f, 0.f, 0.f, 0.f};

  const int tw = t & 192;  // wave base within 256 threads

  for (int ks = 0; ks < KSTEPS; ++ks) {
    const int kel = ks * 32;
    // A tiles: 512 chunks each (128 rows x 4 chunks)
#pragma unroll
    for (int j = 0; j < 2; ++j) {
      int e = j * 256 + t;  // linear LDS 16B-chunk index
      int rp = e >> 3;
      int cc = (e & 7) ^ (rp & 7);          // pre-swizzled source chunk
      int row = (rp << 1) | (cc >> 2);
      size_t goff = (size_t)row * DIM + kel + (cc & 3) * 8;  // ushort units
      int loff = (j * 256 + tw) * 8;                         // wave-uniform LDS base
      async16(gah + goff, la_hi + loff);
      async16(gal + goff, la_lo + loff);
    }
    // B tiles: 1024 chunks each (256 rows x 4 chunks)
#pragma unroll
    for (int j = 0; j < 4; ++j) {
      int e = j * 256 + t;
      int rp = e >> 3;
      int cc = (e & 7) ^ (rp & 7);
      int row = (rp << 1) | (cc >> 2);
      size_t goff = (size_t)row * DIM + kel + (cc & 3) * 8;
      int loff = (j * 256 + tw) * 8;
      async16(gbh + goff, lb_hi + loff);
      async16(gbl + goff, lb_lo + loff);
    }
    __syncthreads();

    short8 ah[4], al[4];
#pragma unroll
    for (int mi = 0; mi < 4; ++mi) {
      int r = swz(wy * 64 + mi * 16 + lm, q);
      ah[mi] = *(const short8*)(la_hi + r);
      al[mi] = *(const short8*)(la_lo + r);
    }
#pragma unroll
    for (int h = 0; h < 2; ++h) {
      short8 bh[4], bl[4];
#pragma unroll
      for (int nj = 0; nj < 4; ++nj) {
        int r = swz(wx * 128 + (h * 4 + nj) * 16 + lm, q);
        bh[nj] = *(const short8*)(lb_hi + r);
        bl[nj] = *(const short8*)(lb_lo + r);
      }
#pragma unroll
      for (int mi = 0; mi < 4; ++mi)
#pragma unroll
        for (int nj = 0; nj < 4; ++nj) {
          int ni = h * 4 + nj;
          acc[mi][ni] = __builtin_amdgcn_mfma_f32_16x16x32_bf16(ah[mi], bh[nj], acc[mi][ni], 0, 0, 0);
          acc[mi][ni] = __builtin_amdgcn_mfma_f32_16x16x32_bf16(ah[mi], bl[nj], acc[mi][ni], 0, 0, 0);
          acc[mi][ni] = __builtin_amdgcn_mfma_f32_16x16x32_bf16(al[mi], bh[nj], acc[mi][ni], 0, 0, 0);
        }
    }
    __syncthreads();
  }

  // per-row argmax over this block's 256 style columns
  // C layout (16x16x32): col = lane&15, row = (lane>>4)*4 + reg
#pragma unroll
  for (int mi = 0; mi < 4; ++mi) {
#pragma unroll
    for (int r = 0; r < 4; ++r) {
      float bv = acc[mi][0][r];
      int bn = 0;
#pragma unroll
      for (int ni = 1; ni < 8; ++ni) {
        float v = acc[mi][ni][r];
        if (v > bv) { bv = v; bn = ni; }
      }
      u32 colg = (u32)(sb * 256 + wx * 128 + bn * 16 + lm);
      u64 key = ((u64)fkey(bv) << 32) | (u64)(0xFFFFFFFFu - colg);
#pragma unroll
      for (int off = 8; off >= 1; off >>= 1) {
        u64 o = __shfl_xor((unsigned long long)key, off, 64);
        if (o > key) key = o;
      }
      if (lm == 0) red[wy * 64 + mi * 16 + q * 4 + r][wx] = key;
    }
  }
  __syncthreads();
  if (t < 128) {
    u64 k0 = red[t][0], k1 = red[t][1];
    u64 b = k0 > k1 ? k0 : k1;
    partial[((size_t)(cb * 128 + t)) * 64 + sb] = b;
  }
}

// ---------- kernel 4: final 64-way reduce + gather ----------

__global__ __launch_bounds__(256) void argmax_gather_kernel(
    const u64* __restrict__ partial, const float* __restrict__ fs, float* __restrict__ out) {
  const int m = blockIdx.x, t = threadIdx.x;
  __shared__ u64 sbest;
  if (t < 64) {
    u64 key = partial[(size_t)m * 64 + t];
#pragma unroll
    for (int off = 32; off >= 1; off >>= 1) {
      u64 o = __shfl_xor((unsigned long long)key, off, 64);
      if (o > key) key = o;
    }
    if (t == 0) sbest = key;
  }
  __syncthreads();
  u64 best = sbest;
  u32 col = 0xFFFFFFFFu - (u32)best;
  const float4* src = (const float4*)(fs + (size_t)col * DIM);
  float4* dst = (float4*)(out + (size_t)m * DIM);
  for (int i = t; i < D4; i += 256) dst[i] = src[i];
}

// ---------- launch ----------

extern "C" void kernel_launch(void* const* d_in, const int* in_sizes, int n_in,
                              void* d_out, int out_size, void* d_ws, size_t ws_size,
                              hipStream_t stream) {
  const float* fc = (const float*)d_in[0];
  const float* fs = (const float*)d_in[1];
  float* out = (float*)d_out;

  ushort_t* c_hi = (ushort_t*)d_ws;
  ushort_t* c_lo = c_hi + (size_t)NC_ * DIM;
  ushort_t* s_hi = c_lo + (size_t)NC_ * DIM;
  ushort_t* s_lo = s_hi + (size_t)NS_ * DIM;
  u64* partial = (u64*)(s_lo + (size_t)NS_ * DIM);  // 16384 * 64 u64

  content_split_kernel<<<(NC_ * DIM / 4 + 255) / 256, 256, 0, stream>>>(fc, c_hi, c_lo);
  style_split_kernel<<<NS_, 256, 0, stream>>>(fs, s_hi, s_lo);
  sim_argmax_kernel<<<8192, 256, 0, stream>>>(c_hi, c_lo, s_hi, s_lo, partial);
  argmax_gather_kernel<<<NC_, 256, 0, stream>>>(partial, fs, out);
}

// Round 4
// 3764.825 us; speedup vs baseline: 1.3434x; 1.0091x over previous
//
#include <hip/hip_runtime.h>
#include <stdint.h>

typedef unsigned short ushort_t;
typedef unsigned int u32;
typedef unsigned long long u64;

#define NC_ 16384
#define NS_ 16384
#define DIM 2688
#define D4 (DIM / 4)       // 672 float4 per row
#define KSTEPS (DIM / 32)  // 84

typedef __attribute__((ext_vector_type(8))) short short8;
typedef __attribute__((ext_vector_type(4))) float f32x4;

// ---------- helpers ----------

__device__ inline ushort_t f2bf(float x) {
  u32 u = __float_as_uint(x);
  u32 r = u + 0x7FFFu + ((u >> 16) & 1u);  // RNE
  return (ushort_t)(r >> 16);
}
__device__ inline float bf2f(ushort_t b) { return __uint_as_float(((u32)b) << 16); }

// monotone float -> uint mapping (finite inputs)
__device__ inline u32 fkey(float f) {
  u32 u = __float_as_uint(f);
  return (u & 0x80000000u) ? ~u : (u | 0x80000000u);
}

__device__ inline void async16(const void* g, void* l) {
  __builtin_amdgcn_global_load_lds(
      (const __attribute__((address_space(1))) u32*)g,
      (__attribute__((address_space(3))) u32*)l, 16, 0, 0);
}

// Swizzled ushort offset of (row r, 16B-chunk q) within a [rows][32-ushort] tile.
// Rows paired into 128B lines of 8 chunks; chunk index XOR'd with row-pair index
// so each 16-lane quarter-wave read covers all 8 bank slots exactly twice
// (2-way = free). Verified 0 SQ_LDS_BANK_CONFLICT with the 16x16x32 read pattern.
__device__ inline int swz(int r, int q) {
  return ((r >> 1) << 6) + (((((r & 1) << 2) | q) ^ ((r >> 1) & 7)) << 3);
}

// ---------- kernel 1: split content fp32 -> bf16 hi/lo ----------

__global__ __launch_bounds__(256) void content_split_kernel(
    const float* __restrict__ fc, ushort_t* __restrict__ c_hi, ushort_t* __restrict__ c_lo) {
  size_t i = (size_t)blockIdx.x * 256 + threadIdx.x;
  if (i >= (size_t)NC_ * DIM / 4) return;
  float4 v = ((const float4*)fc)[i];
  ushort4 h, l;
  h.x = f2bf(v.x); l.x = f2bf(v.x - bf2f(h.x));
  h.y = f2bf(v.y); l.y = f2bf(v.y - bf2f(h.y));
  h.z = f2bf(v.z); l.z = f2bf(v.z - bf2f(h.z));
  h.w = f2bf(v.w); l.w = f2bf(v.w - bf2f(h.w));
  ((ushort4*)c_hi)[i] = h;
  ((ushort4*)c_lo)[i] = l;
}

// ---------- kernel 2: style row-normalize + split ----------

__global__ __launch_bounds__(256) void style_split_kernel(
    const float* __restrict__ fs, ushort_t* __restrict__ s_hi, ushort_t* __restrict__ s_lo) {
  const int s = blockIdx.x, t = threadIdx.x;
  const float4* row = (const float4*)(fs + (size_t)s * DIM);
  float ss = 0.f;
  for (int i = t; i < D4; i += 256) {
    float4 v = row[i];
    ss += v.x * v.x + v.y * v.y + v.z * v.z + v.w * v.w;
  }
#pragma unroll
  for (int off = 32; off >= 1; off >>= 1) ss += __shfl_xor(ss, off, 64);
  __shared__ float wsum[4];
  if ((t & 63) == 0) wsum[t >> 6] = ss;
  __syncthreads();
  float scale = rsqrtf(wsum[0] + wsum[1] + wsum[2] + wsum[3] + 1e-8f);
  ushort4* h4 = (ushort4*)(s_hi + (size_t)s * DIM);
  ushort4* l4 = (ushort4*)(s_lo + (size_t)s * DIM);
  for (int i = t; i < D4; i += 256) {
    float4 v = row[i];
    float x = v.x * scale, y = v.y * scale, z = v.z * scale, w = v.w * scale;
    ushort4 h, l;
    h.x = f2bf(x); l.x = f2bf(x - bf2f(h.x));
    h.y = f2bf(y); l.y = f2bf(y - bf2f(h.y));
    h.z = f2bf(z); l.z = f2bf(z - bf2f(h.z));
    h.w = f2bf(w); l.w = f2bf(w - bf2f(h.w));
    h4[i] = h;
    l4[i] = l;
  }
}

// ---------- kernel 3: 256x256-tile sim GEMM (bf16x3), double-buffered, counted vmcnt ----------
// 512 threads, 8 waves in 2(M)x4(N) grid, wave tile 128x64, acc[8][4].
// LDS: 2 x (A 32K + B 32K) = 128 KiB double-buffer + 8 KiB red = 136 KiB, 1 block/CU.
// Schedule (catalog T3-minimum + T4): per K-step issue next tile's 8 global_load_lds,
// s_waitcnt vmcnt(8) (drain only PREVIOUS tile's loads; next's stay in flight across
// the barrier), s_barrier, ds_read+MFMA, s_barrier. Never vmcnt(0) in main loop.
// partial[m * 64 + sb] = packed (fkey(max sim) << 32) | (0xFFFFFFFF - argmax_col)

__global__ __launch_bounds__(512, 2) void sim_argmax_kernel(
    const ushort_t* __restrict__ c_hi, const ushort_t* __restrict__ c_lo,
    const ushort_t* __restrict__ s_hi, const ushort_t* __restrict__ s_lo,
    u64* __restrict__ partial) {
  __shared__ __align__(16) ushort_t lds[65536];  // 128 KiB: two 64 KiB buffers
  __shared__ u64 red[256][4];                    // 8 KiB

  const int t = threadIdx.x;
  const int bid = blockIdx.x;  // 4096 blocks: 64 cb x 64 sb
  // 8x8 block supertiles for LLC/L2 locality
  const int grp = bid >> 6;   // 0..63
  const int wi = bid & 63;
  const int cb = (grp & 7) * 8 + (wi & 7);    // 0..63
  const int sb = (grp >> 3) * 8 + (wi >> 3);  // 0..63

  const ushort_t* gah = c_hi + (size_t)cb * 256 * DIM;
  const ushort_t* gal = c_lo + (size_t)cb * 256 * DIM;
  const ushort_t* gbh = s_hi + (size_t)sb * 256 * DIM;
  const ushort_t* gbl = s_lo + (size_t)sb * 256 * DIM;

  const int lane = t & 63;
  const int wave = t >> 6;
  const int wy = wave >> 2, wx = wave & 3;  // 2x4 wave grid; wave tile 128(M) x 64(N)
  const int lm = lane & 15, q = lane >> 4;
  const int wb = t & 448;  // wave base within 512 threads

  f32x4 acc[8][4];
#pragma unroll
  for (int i = 0; i < 8; i++)
#pragma unroll
    for (int j = 0; j < 4; j++) acc[i][j] = (f32x4){0.f, 0.f, 0.f, 0.f};

  // stage tile ks into buffer b: 8 global_load_lds per thread (A hi/lo, B hi/lo).
  // Each part is 1024 chunks = 2 rounds of 512 threads. Source pre-swizzled to
  // match the swz() read layout (LDS dest linear per wave: base + lane*16).
  auto stage = [&](int ks, int b) {
    const int kel = ks * 32;
    ushort_t* base = lds + b * 32768;
#pragma unroll
    for (int j = 0; j < 2; ++j) {
      int e = j * 512 + t;                 // linear LDS 16B-chunk index
      int rp = e >> 3;
      int cc = (e & 7) ^ (rp & 7);         // pre-swizzled source chunk
      int row = (rp << 1) | (cc >> 2);
      size_t goff = (size_t)row * DIM + kel + (cc & 3) * 8;  // ushort units
      int loff = (j * 512 + wb) * 8;                         // wave-uniform LDS base
      async16(gah + goff, base + loff);
      async16(gal + goff, base + 8192 + loff);
      async16(gbh + goff, base + 16384 + loff);
      async16(gbl + goff, base + 24576 + loff);
    }
  };

  auto compute = [&](int b) {
    ushort_t* base = lds + b * 32768;
    const ushort_t* lah = base;
    const ushort_t* lal = base + 8192;
    const ushort_t* lbh = base + 16384;
    const ushort_t* lbl = base + 24576;
    short8 ah[8], al[8];
#pragma unroll
    for (int mi = 0; mi < 8; ++mi) {
      int r = swz(wy * 128 + mi * 16 + lm, q);
      ah[mi] = *(const short8*)(lah + r);
      al[mi] = *(const short8*)(lal + r);
    }
#pragma unroll
    for (int nj = 0; nj < 4; ++nj) {
      int r = swz(wx * 64 + nj * 16 + lm, q);
      short8 bh = *(const short8*)(lbh + r);
      short8 bl = *(const short8*)(lbl + r);
#pragma unroll
      for (int mi = 0; mi < 8; ++mi) {
        acc[mi][nj] = __builtin_amdgcn_mfma_f32_16x16x32_bf16(ah[mi], bh, acc[mi][nj], 0, 0, 0);
        acc[mi][nj] = __builtin_amdgcn_mfma_f32_16x16x32_bf16(ah[mi], bl, acc[mi][nj], 0, 0, 0);
        acc[mi][nj] = __builtin_amdgcn_mfma_f32_16x16x32_bf16(al[mi], bh, acc[mi][nj], 0, 0, 0);
      }
    }
  };

  stage(0, 0);
  for (int ks = 0; ks < KSTEPS - 1; ++ks) {
    stage(ks + 1, (ks + 1) & 1);
    // wait only for the PREVIOUS tile's 8 loads; the 8 just issued stay in flight
    asm volatile("s_waitcnt vmcnt(8)" ::: "memory");
    __builtin_amdgcn_s_barrier();
    compute(ks & 1);
    // protect buf[cur] from being restaged by fast waves next iteration
    __builtin_amdgcn_s_barrier();
  }
  asm volatile("s_waitcnt vmcnt(0)" ::: "memory");
  __builtin_amdgcn_s_barrier();
  compute((KSTEPS - 1) & 1);

  // per-row argmax over this block's 256 style columns
  // C layout (16x16x32): col = lane&15, row = (lane>>4)*4 + reg
#pragma unroll
  for (int mi = 0; mi < 8; ++mi) {
#pragma unroll
    for (int r = 0; r < 4; ++r) {
      float bv = acc[mi][0][r];
      int bn = 0;
#pragma unroll
      for (int nj = 1; nj < 4; ++nj) {
        float v = acc[mi][nj][r];
        if (v > bv) { bv = v; bn = nj; }
      }
      u32 colg = (u32)(sb * 256 + wx * 64 + bn * 16 + lm);
      u64 key = ((u64)fkey(bv) << 32) | (u64)(0xFFFFFFFFu - colg);
#pragma unroll
      for (int off = 8; off >= 1; off >>= 1) {
        u64 o = __shfl_xor((unsigned long long)key, off, 64);
        if (o > key) key = o;
      }
      if (lm == 0) red[wy * 128 + mi * 16 + q * 4 + r][wx] = key;
    }
  }
  __syncthreads();
  if (t < 256) {
    u64 k0 = red[t][0], k1 = red[t][1], k2 = red[t][2], k3 = red[t][3];
    u64 a = k0 > k1 ? k0 : k1;
    u64 c = k2 > k3 ? k2 : k3;
    u64 b = a > c ? a : c;
    partial[((size_t)(cb * 256 + t)) * 64 + sb] = b;
  }
}

// ---------- kernel 4: final 64-way reduce + gather ----------

__global__ __launch_bounds__(256) void argmax_gather_kernel(
    const u64* __restrict__ partial, const float* __restrict__ fs, float* __restrict__ out) {
  const int m = blockIdx.x, t = threadIdx.x;
  __shared__ u64 sbest;
  if (t < 64) {
    u64 key = partial[(size_t)m * 64 + t];
#pragma unroll
    for (int off = 32; off >= 1; off >>= 1) {
      u64 o = __shfl_xor((unsigned long long)key, off, 64);
      if (o > key) key = o;
    }
    if (t == 0) sbest = key;
  }
  __syncthreads();
  u64 best = sbest;
  u32 col = 0xFFFFFFFFu - (u32)best;
  const float4* src = (const float4*)(fs + (size_t)col * DIM);
  float4* dst = (float4*)(out + (size_t)m * DIM);
  for (int i = t; i < D4; i += 256) dst[i] = src[i];
}

// ---------- launch ----------

extern "C" void kernel_launch(void* const* d_in, const int* in_sizes, int n_in,
                              void* d_out, int out_size, void* d_ws, size_t ws_size,
                              hipStream_t stream) {
  const float* fc = (const float*)d_in[0];
  const float* fs = (const float*)d_in[1];
  float* out = (float*)d_out;

  ushort_t* c_hi = (ushort_t*)d_ws;
  ushort_t* c_lo = c_hi + (size_t)NC_ * DIM;
  ushort_t* s_hi = c_lo + (size_t)NC_ * DIM;
  ushort_t* s_lo = s_hi + (size_t)NS_ * DIM;
  u64* partial = (u64*)(s_lo + (size_t)NS_ * DIM);  // 16384 * 64 u64

  content_split_kernel<<<(NC_ * DIM / 4 + 255) / 256, 256, 0, stream>>>(fc, c_hi, c_lo);
  style_split_kernel<<<NS_, 256, 0, stream>>>(fs, s_hi, s_lo);
  sim_argmax_kernel<<<4096, 512, 0, stream>>>(c_hi, c_lo, s_hi, s_lo, partial);
  argmax_gather_kernel<<<NC_, 256, 0, stream>>>(partial, fs, out);
}